// Round 10
// baseline (769.597 us; speedup 1.0000x reference)
//
#include <hip/hip_runtime.h>

typedef unsigned short u16;
typedef unsigned int u32;
typedef float f32x4 __attribute__((ext_vector_type(4)));
typedef __bf16 bf16x8 __attribute__((ext_vector_type(8)));

__device__ __forceinline__ u16 f2bf(float f) {
  unsigned u = __builtin_bit_cast(unsigned, f);
  u += 0x7FFFu + ((u >> 16) & 1u);
  return (u16)(u >> 16);
}

// one-instruction packed f32x2 -> bf16x2 (RNE)
__device__ __forceinline__ u32 pack2(float a, float b) {
  u32 r;
  asm("v_cvt_pk_bf16_f32 %0, %1, %2" : "=v"(r) : "v"(a), "v"(b));
  return r;
}

// in-wave transpose of a pair of gemmT acc tiles into an MFMA fragment bf16x8
__device__ __forceinline__ bf16x8 xpose_tile(const f32x4 t0, const f32x4 t1,
                                             int srcA, int srcB, bool hi) {
  u32 s0 = pack2(t0[0], t0[1]);
  u32 s1 = pack2(t0[2], t0[3]);
  u32 s2 = pack2(t1[0], t1[1]);
  u32 s3 = pack2(t1[2], t1[3]);
  u32 a00 = (u32)__shfl((int)s0, srcA), a20 = (u32)__shfl((int)s2, srcA);
  u32 a01 = (u32)__shfl((int)s1, srcA), a21 = (u32)__shfl((int)s3, srcA);
  u32 b00 = (u32)__shfl((int)s0, srcB), b20 = (u32)__shfl((int)s2, srcB);
  u32 b01 = (u32)__shfl((int)s1, srcB), b21 = (u32)__shfl((int)s3, srcB);
  uint4 u;
  u.x = hi ? a20 : a00;
  u.y = hi ? a21 : a01;
  u.z = hi ? b20 : b00;
  u.w = hi ? b21 : b01;
  return __builtin_bit_cast(bf16x8, u);
}

// ---- prep: weights f32->bf16, rel-pos bias -> [8][64][64] f32
__global__ void prep_kern(const float* __restrict__ qw_f, const float* __restrict__ kvw_f,
                          const float* __restrict__ pjw_f, const float* __restrict__ rpb,
                          u16* __restrict__ qw, u16* __restrict__ kvw, u16* __restrict__ pjw,
                          float* __restrict__ biasf) {
  int i = blockIdx.x * 256 + threadIdx.x;
  if (i < 65536) {
    qw[i] = f2bf(qw_f[i]);
  } else if (i < 196608) {
    kvw[i - 65536] = f2bf(kvw_f[i - 65536]);
  } else if (i < 262144) {
    pjw[i - 196608] = f2bf(pjw_f[i - 196608]);
  } else if (i < 294912) {
    int t = i - 262144;                 // [h][n][m]
    int h = t >> 12, n = (t >> 6) & 63, m = t & 63;
    int r1 = n >> 3, c1 = n & 7, r2 = m >> 3, c2 = m & 7;
    int rp = (r1 - r2 + 7) * 15 + (c1 - c2 + 7);
    biasf[t] = rpb[rp * 8 + h];
  }
}

#define XROW 528

// ===================== K1: QKV + attention -> O fragments =====================
// 256 threads = 4 waves; wave wv owns channels [wv*64, wv*64+64) = heads 2wv, 2wv+1.
// ONE 33.8 KB stage buffer (ref then adj) -> 4 blocks/CU at 128 VGPR.
// Of: uint4[((b*8+h)*4+nt)*64 + l] : lane(lr,lq) = O[t=16nt+lr][cin=h*32+8lq..+7]
#define K1_LDS 33792

__global__ __launch_bounds__(256, 4) void qkvattn_kern(
    const float* __restrict__ xr_g, const float* __restrict__ xa_g,
    const float* __restrict__ mask_g,
    const float* __restrict__ qb_g, const float* __restrict__ kvb_g,
    const u16* __restrict__ qw, const u16* __restrict__ kvw,
    const float* __restrict__ biasf, uint4* __restrict__ Of, int nW) {
  extern __shared__ char smem[];
  const int tid = threadIdx.x;
  const int l = tid & 63, wv = tid >> 6;  // wv 0..3
  const int lr = l & 15, lq = l >> 4;
  const int b = blockIdx.x;
  const int wd = b % nW;
  const float scale = 0.17677669529663687f;  // 1/sqrt(32)
  const int srcA = lr + 32 * (lq & 1);
  const int srcB = srcA + 16;
  const bool hi = (lq >> 1) != 0;
  const int kl = 8 * lq;
  const int row0 = wv * 64 + lr;

  // ---- stage one [64][256] f32 tile into S as bf16 [64][264]
  auto stage = [&](const float* src) {
#pragma unroll 4
    for (int it = 0; it < 16; ++it) {
      int flat = it * 256 + tid;
      int t = flat >> 6, c4 = (flat & 63) << 2;
      float4 v = *(const float4*)(src + t * 256 + c4);
      uint2 w;
      w.x = pack2(v.x, v.y);
      w.y = pack2(v.z, v.w);
      *(uint2*)(smem + t * XROW + c4 * 2) = w;
    }
  };

  stage(xr_g + (size_t)b * 16384);
  __syncthreads();  // B1: ref staged

  bf16x8 bfr[2][4], afr[2][4];

  // ---- Q-gemm: 64 channels (4 row-tiles), 64 tokens -> xpose -> bfr[h2][nt]
  {
    f32x4 qacc[4][4];
#pragma unroll
    for (int i = 0; i < 4; ++i)
#pragma unroll
      for (int j = 0; j < 4; ++j) qacc[i][j] = {0.f, 0.f, 0.f, 0.f};
#pragma unroll 2
    for (int kk = 0; kk < 8; ++kk) {
      int c = kk * 32 + kl;
      bf16x8 a0 = *(const bf16x8*)(qw + (row0) * 256 + c);
      bf16x8 a1 = *(const bf16x8*)(qw + (row0 + 16) * 256 + c);
      bf16x8 a2 = *(const bf16x8*)(qw + (row0 + 32) * 256 + c);
      bf16x8 a3 = *(const bf16x8*)(qw + (row0 + 48) * 256 + c);
#pragma unroll
      for (int nt = 0; nt < 4; ++nt) {
        bf16x8 bt = *(const bf16x8*)(smem + (nt * 16 + lr) * XROW + c * 2);
        qacc[0][nt] = __builtin_amdgcn_mfma_f32_16x16x32_bf16(a0, bt, qacc[0][nt], 0, 0, 0);
        qacc[1][nt] = __builtin_amdgcn_mfma_f32_16x16x32_bf16(a1, bt, qacc[1][nt], 0, 0, 0);
        qacc[2][nt] = __builtin_amdgcn_mfma_f32_16x16x32_bf16(a2, bt, qacc[2][nt], 0, 0, 0);
        qacc[3][nt] = __builtin_amdgcn_mfma_f32_16x16x32_bf16(a3, bt, qacc[3][nt], 0, 0, 0);
      }
    }
#pragma unroll
    for (int rt = 0; rt < 4; ++rt) {
      float4 b4 = *(const float4*)(qb_g + wv * 64 + rt * 16 + 4 * lq);
#pragma unroll
      for (int nt = 0; nt < 4; ++nt) {
        qacc[rt][nt][0] = (qacc[rt][nt][0] + b4.x) * scale;
        qacc[rt][nt][1] = (qacc[rt][nt][1] + b4.y) * scale;
        qacc[rt][nt][2] = (qacc[rt][nt][2] + b4.z) * scale;
        qacc[rt][nt][3] = (qacc[rt][nt][3] + b4.w) * scale;
      }
    }
#pragma unroll
    for (int h2 = 0; h2 < 2; ++h2)
#pragma unroll
      for (int nt = 0; nt < 4; ++nt)
        bfr[h2][nt] = xpose_tile(qacc[2 * h2][nt], qacc[2 * h2 + 1][nt], srcA, srcB, hi);
  }
  __syncthreads();  // B2: all Q reads of S complete

  stage(xa_g + (size_t)b * 16384);
  __syncthreads();  // B3: adj staged

  // ---- K-gemm -> xpose -> afr[h2][mt]
  {
    f32x4 kacc[4][4];
#pragma unroll
    for (int i = 0; i < 4; ++i)
#pragma unroll
      for (int j = 0; j < 4; ++j) kacc[i][j] = {0.f, 0.f, 0.f, 0.f};
#pragma unroll 2
    for (int kk = 0; kk < 8; ++kk) {
      int c = kk * 32 + kl;
      bf16x8 a0 = *(const bf16x8*)(kvw + (row0) * 256 + c);
      bf16x8 a1 = *(const bf16x8*)(kvw + (row0 + 16) * 256 + c);
      bf16x8 a2 = *(const bf16x8*)(kvw + (row0 + 32) * 256 + c);
      bf16x8 a3 = *(const bf16x8*)(kvw + (row0 + 48) * 256 + c);
#pragma unroll
      for (int nt = 0; nt < 4; ++nt) {
        bf16x8 bt = *(const bf16x8*)(smem + (nt * 16 + lr) * XROW + c * 2);
        kacc[0][nt] = __builtin_amdgcn_mfma_f32_16x16x32_bf16(a0, bt, kacc[0][nt], 0, 0, 0);
        kacc[1][nt] = __builtin_amdgcn_mfma_f32_16x16x32_bf16(a1, bt, kacc[1][nt], 0, 0, 0);
        kacc[2][nt] = __builtin_amdgcn_mfma_f32_16x16x32_bf16(a2, bt, kacc[2][nt], 0, 0, 0);
        kacc[3][nt] = __builtin_amdgcn_mfma_f32_16x16x32_bf16(a3, bt, kacc[3][nt], 0, 0, 0);
      }
    }
#pragma unroll
    for (int rt = 0; rt < 4; ++rt) {
      float4 b4 = *(const float4*)(kvb_g + wv * 64 + rt * 16 + 4 * lq);
#pragma unroll
      for (int nt = 0; nt < 4; ++nt) {
        kacc[rt][nt][0] += b4.x;
        kacc[rt][nt][1] += b4.y;
        kacc[rt][nt][2] += b4.z;
        kacc[rt][nt][3] += b4.w;
      }
    }
#pragma unroll
    for (int h2 = 0; h2 < 2; ++h2)
#pragma unroll
      for (int nt = 0; nt < 4; ++nt)
        afr[h2][nt] = xpose_tile(kacc[2 * h2][nt], kacc[2 * h2 + 1][nt], srcA, srcB, hi);
  }

  // ---- V-gemm (non-transposed) -> xpose -> vfr[h2][kk][cg]
  bf16x8 vfr[2][2][2];
  {
    f32x4 vacc[4][4];  // [mt tok-tile][ct chan-16-block]
#pragma unroll
    for (int i = 0; i < 4; ++i)
#pragma unroll
      for (int j = 0; j < 4; ++j) vacc[i][j] = {0.f, 0.f, 0.f, 0.f};
    const int vrow0 = 256 + wv * 64 + lr;
#pragma unroll 2
    for (int kk = 0; kk < 8; ++kk) {
      int c = kk * 32 + kl;
      bf16x8 b0 = *(const bf16x8*)(kvw + (vrow0) * 256 + c);
      bf16x8 b1 = *(const bf16x8*)(kvw + (vrow0 + 16) * 256 + c);
      bf16x8 b2 = *(const bf16x8*)(kvw + (vrow0 + 32) * 256 + c);
      bf16x8 b3 = *(const bf16x8*)(kvw + (vrow0 + 48) * 256 + c);
#pragma unroll
      for (int mt = 0; mt < 4; ++mt) {
        bf16x8 at = *(const bf16x8*)(smem + (mt * 16 + lr) * XROW + c * 2);
        vacc[mt][0] = __builtin_amdgcn_mfma_f32_16x16x32_bf16(at, b0, vacc[mt][0], 0, 0, 0);
        vacc[mt][1] = __builtin_amdgcn_mfma_f32_16x16x32_bf16(at, b1, vacc[mt][1], 0, 0, 0);
        vacc[mt][2] = __builtin_amdgcn_mfma_f32_16x16x32_bf16(at, b2, vacc[mt][2], 0, 0, 0);
        vacc[mt][3] = __builtin_amdgcn_mfma_f32_16x16x32_bf16(at, b3, vacc[mt][3], 0, 0, 0);
      }
    }
#pragma unroll
    for (int ct = 0; ct < 4; ++ct) {
      float bv = kvb_g[256 + wv * 64 + ct * 16 + lr];
#pragma unroll
      for (int mt = 0; mt < 4; ++mt)
#pragma unroll
        for (int j = 0; j < 4; ++j) vacc[mt][ct][j] += bv;
    }
#pragma unroll
    for (int h2 = 0; h2 < 2; ++h2)
#pragma unroll
      for (int kk = 0; kk < 2; ++kk)
#pragma unroll
        for (int cg = 0; cg < 2; ++cg)
          vfr[h2][kk][cg] =
              xpose_tile(vacc[2 * kk][2 * h2 + cg], vacc[2 * kk + 1][2 * h2 + cg], srcA, srcB, hi);
  }

  // ---- per-head attention (sequential; sacc reused; compile-time indices)
#pragma unroll
  for (int h2 = 0; h2 < 2; ++h2) {
    const int h = wv * 2 + h2;

    // QK^T with C = bias + mask
    f32x4 sacc[4][4];  // attnT[m=16mt+4lq+j][n=16nt+lr]
    {
      const float* bias_h = biasf + h * 4096;
      const float* mask_w = mask_g + (size_t)wd * 4096;
#pragma unroll
      for (int nt = 0; nt < 4; ++nt) {
        int n = nt * 16 + lr;
#pragma unroll
        for (int mt = 0; mt < 4; ++mt) {
          float4 bi = *(const float4*)(bias_h + n * 64 + mt * 16 + 4 * lq);
          float4 m4 = *(const float4*)(mask_w + n * 64 + mt * 16 + 4 * lq);
          sacc[mt][nt][0] = bi.x + m4.x;
          sacc[mt][nt][1] = bi.y + m4.y;
          sacc[mt][nt][2] = bi.z + m4.z;
          sacc[mt][nt][3] = bi.w + m4.w;
        }
      }
    }
#pragma unroll
    for (int mt = 0; mt < 4; ++mt)
#pragma unroll
      for (int nt = 0; nt < 4; ++nt)
        sacc[mt][nt] = __builtin_amdgcn_mfma_f32_16x16x32_bf16(afr[h2][mt], bfr[h2][nt],
                                                               sacc[mt][nt], 0, 0, 0);

    // softmax (register-only)
    float rden[4];
#pragma unroll
    for (int nt = 0; nt < 4; ++nt) {
      float lmx = -1e30f;
#pragma unroll
      for (int mt = 0; mt < 4; ++mt)
        lmx = fmaxf(lmx, fmaxf(fmaxf(sacc[mt][nt][0], sacc[mt][nt][1]),
                               fmaxf(sacc[mt][nt][2], sacc[mt][nt][3])));
      lmx = fmaxf(lmx, __shfl_xor(lmx, 16));
      lmx = fmaxf(lmx, __shfl_xor(lmx, 32));
      float ls = 0.f;
#pragma unroll
      for (int mt = 0; mt < 4; ++mt) {
#pragma unroll
        for (int j = 0; j < 4; ++j) {
          float e = __expf(sacc[mt][nt][j] - lmx);
          sacc[mt][nt][j] = e;
          ls += e;
        }
      }
      ls += __shfl_xor(ls, 16);
      ls += __shfl_xor(ls, 32);
      rden[nt] = 1.0f / ls;
    }

    // P transpose -> pfr[kk][nt]
    bf16x8 pfr[2][4];
#pragma unroll
    for (int kk = 0; kk < 2; ++kk)
#pragma unroll
      for (int nt = 0; nt < 4; ++nt)
        pfr[kk][nt] = xpose_tile(sacc[2 * kk][nt], sacc[2 * kk + 1][nt], srcA, srcB, hi);

    // PV
    f32x4 oacc[2][4];
#pragma unroll
    for (int i = 0; i < 2; ++i)
#pragma unroll
      for (int j = 0; j < 4; ++j) oacc[i][j] = {0.f, 0.f, 0.f, 0.f};
#pragma unroll
    for (int kk = 0; kk < 2; ++kk)
#pragma unroll
      for (int nt = 0; nt < 4; ++nt) {
        oacc[0][nt] = __builtin_amdgcn_mfma_f32_16x16x32_bf16(vfr[h2][kk][0], pfr[kk][nt],
                                                              oacc[0][nt], 0, 0, 0);
        oacc[1][nt] = __builtin_amdgcn_mfma_f32_16x16x32_bf16(vfr[h2][kk][1], pfr[kk][nt],
                                                              oacc[1][nt], 0, 0, 0);
      }

    // normalize -> xpose -> Of fragments
#pragma unroll
    for (int nt = 0; nt < 4; ++nt) {
      float r = rden[nt];
#pragma unroll
      for (int j = 0; j < 4; ++j) {
        oacc[0][nt][j] *= r;
        oacc[1][nt][j] *= r;
      }
      bf16x8 f = xpose_tile(oacc[0][nt], oacc[1][nt], srcA, srcB, hi);
      Of[((size_t)(b * 8 + h) * 4 + nt) * 64 + l] = __builtin_bit_cast(uint4, f);
    }
  }
}

// ===================== K2: output projection (no LDS, no barrier) =====================
__global__ __launch_bounds__(512, 4) void proj_kern(
    const uint4* __restrict__ Of, const u16* __restrict__ pjw,
    const float* __restrict__ pb_g, float* __restrict__ out_g) {
  const int tid = threadIdx.x;
  const int l = tid & 63, wv = tid >> 6;
  const int lr = l & 15, lq = l >> 4;
  const int b = blockIdx.x;

  f32x4 acc[4][2];
#pragma unroll
  for (int i = 0; i < 4; ++i)
#pragma unroll
    for (int j = 0; j < 2; ++j) acc[i][j] = {0.f, 0.f, 0.f, 0.f};
  const int kl = 8 * lq;
  const int prow0 = wv * 32 + lr;
#pragma unroll 2
  for (int kk = 0; kk < 8; ++kk) {
    int c = kk * 32 + kl;
    bf16x8 b0 = *(const bf16x8*)(pjw + prow0 * 256 + c);
    bf16x8 b1 = *(const bf16x8*)(pjw + (prow0 + 16) * 256 + c);
#pragma unroll
    for (int mt = 0; mt < 4; ++mt) {
      bf16x8 at = __builtin_bit_cast(bf16x8, Of[((size_t)(b * 8 + kk) * 4 + mt) * 64 + l]);
      acc[mt][0] = __builtin_amdgcn_mfma_f32_16x16x32_bf16(at, b0, acc[mt][0], 0, 0, 0);
      acc[mt][1] = __builtin_amdgcn_mfma_f32_16x16x32_bf16(at, b1, acc[mt][1], 0, 0, 0);
    }
  }
  float* outb = out_g + (size_t)b * 16384;
#pragma unroll
  for (int ntl = 0; ntl < 2; ++ntl) {
    int c = wv * 32 + ntl * 16 + lr;
    float pbv = pb_g[c];
#pragma unroll
    for (int mt = 0; mt < 4; ++mt) {
      int t = mt * 16 + 4 * lq;
      outb[(t + 0) * 256 + c] = acc[mt][ntl][0] + pbv;
      outb[(t + 1) * 256 + c] = acc[mt][ntl][1] + pbv;
      outb[(t + 2) * 256 + c] = acc[mt][ntl][2] + pbv;
      outb[(t + 3) * 256 + c] = acc[mt][ntl][3] + pbv;
    }
  }
}

extern "C" void kernel_launch(void* const* d_in, const int* in_sizes, int n_in,
                              void* d_out, int out_size, void* d_ws, size_t ws_size,
                              hipStream_t stream) {
  const float* ref = (const float*)d_in[0];
  const float* adj = (const float*)d_in[1];
  const float* mask = (const float*)d_in[2];
  const float* q_w = (const float*)d_in[3];
  const float* q_b = (const float*)d_in[4];
  const float* kv_w = (const float*)d_in[5];
  const float* kv_b = (const float*)d_in[6];
  const float* proj_w = (const float*)d_in[7];
  const float* proj_b = (const float*)d_in[8];
  const float* rpb = (const float*)d_in[9];

  u16* qw = (u16*)d_ws;
  u16* kvw = qw + 65536;
  u16* pjw = kvw + 131072;
  float* biasf = (float*)(pjw + 65536);

  prep_kern<<<1152, 256, 0, stream>>>(q_w, kv_w, proj_w, rpb, qw, kvw, pjw, biasf);

  int B = in_sizes[0] / 16384;  // 4096 windows
  int nW = in_sizes[2] / 4096;  // 1024

  // O-fragment buffer: 32 KB/window = 134 MB, at 1 MB offset into ws
  uint4* Of = (uint4*)((char*)d_ws + (1u << 20));

  hipFuncSetAttribute((const void*)qkvattn_kern, hipFuncAttributeMaxDynamicSharedMemorySize,
                      K1_LDS);
  qkvattn_kern<<<B, 256, K1_LDS, stream>>>(ref, adj, mask, q_b, kv_b, qw, kvw, biasf, Of, nW);
  proj_kern<<<B, 512, 0, stream>>>(Of, pjw, proj_b, (float*)d_out);
}

// Round 11
// 406.101 us; speedup vs baseline: 1.8951x; 1.8951x over previous
//
#include <hip/hip_runtime.h>

typedef unsigned short u16;
typedef unsigned int u32;
typedef float f32x4 __attribute__((ext_vector_type(4)));
typedef __bf16 bf16x8 __attribute__((ext_vector_type(8)));

// one-instruction packed f32x2 -> bf16x2 (RNE)
__device__ __forceinline__ u32 pack2(float a, float b) {
  u32 r;
  asm("v_cvt_pk_bf16_f32 %0, %1, %2" : "=v"(r) : "v"(a), "v"(b));
  return r;
}

// in-wave transpose of a pair of gemmT acc tiles into an MFMA fragment bf16x8
__device__ __forceinline__ bf16x8 xpose_tile(const f32x4 t0, const f32x4 t1,
                                             int srcA, int srcB, bool hi) {
  u32 s0 = pack2(t0[0], t0[1]);
  u32 s1 = pack2(t0[2], t0[3]);
  u32 s2 = pack2(t1[0], t1[1]);
  u32 s3 = pack2(t1[2], t1[3]);
  u32 a00 = (u32)__shfl((int)s0, srcA), a20 = (u32)__shfl((int)s2, srcA);
  u32 a01 = (u32)__shfl((int)s1, srcA), a21 = (u32)__shfl((int)s3, srcA);
  u32 b00 = (u32)__shfl((int)s0, srcB), b20 = (u32)__shfl((int)s2, srcB);
  u32 b01 = (u32)__shfl((int)s1, srcB), b21 = (u32)__shfl((int)s3, srcB);
  uint4 u;
  u.x = hi ? a20 : a00;
  u.y = hi ? a21 : a01;
  u.z = hi ? b20 : b00;
  u.w = hi ? b21 : b01;
  return __builtin_bit_cast(bf16x8, u);
}

// ---- prep: permute weights/bias/mask into per-wave fragment order (coalesced loads)
// weight frag: dst[((R*8+kk)*64+l)] = W[ro + R*16 + (l&15)][kk*32 + 8*(l>>4) .. +7] (bf16x8)
// bias/mask frag: dst[((·*4+nt)*4+mt)*64+l] = M[nt*16+(l&15)][mt*16+4*(l>>4) .. +3] (float4)
__global__ void prep_kern(const float* __restrict__ qw_f, const float* __restrict__ kvw_f,
                          const float* __restrict__ pjw_f, const float* __restrict__ rpb,
                          const float* __restrict__ mask_g,
                          uint4* __restrict__ qwt, uint4* __restrict__ kwt,
                          uint4* __restrict__ vwt, uint4* __restrict__ pjwt,
                          float4* __restrict__ biasT, float4* __restrict__ maskT, int nW) {
  int i = blockIdx.x * 256 + threadIdx.x;
  auto wxf = [&](const float* W, int ro, int idx, uint4* dst) {
    int l = idx & 63, kk = (idx >> 6) & 7, R = idx >> 9;
    const float* s = W + (ro + R * 16 + (l & 15)) * 256 + kk * 32 + 8 * (l >> 4);
    uint4 o;
    o.x = pack2(s[0], s[1]);
    o.y = pack2(s[2], s[3]);
    o.z = pack2(s[4], s[5]);
    o.w = pack2(s[6], s[7]);
    dst[idx] = o;
  };
  if (i < 32768) {
    wxf(qw_f, 0, i, qwt);
  } else if (i < 65536) {
    wxf(kvw_f, 0, i - 32768, kwt);
  } else if (i < 98304) {
    wxf(kvw_f, 256, i - 65536, vwt);
  } else if (i < 131072) {
    wxf(pjw_f, 0, i - 98304, pjwt);
  } else if (i < 139264) {
    int j = i - 131072;  // [h][nt][mt][l]
    int l = j & 63, mt = (j >> 6) & 3, nt = (j >> 8) & 3, h = j >> 10;
    int n = nt * 16 + (l & 15), m0 = mt * 16 + 4 * (l >> 4);
    float4 o;
    float* po = (float*)&o;
#pragma unroll
    for (int e = 0; e < 4; ++e) {
      int m = m0 + e;
      int rp = ((n >> 3) - (m >> 3) + 7) * 15 + ((n & 7) - (m & 7) + 7);
      po[e] = rpb[rp * 8 + h];
    }
    biasT[j] = o;
  } else {
    int k = i - 139264;  // [wd][nt][mt][l]
    if (k < nW * 1024) {
      int l = k & 63, mt = (k >> 6) & 3, nt = (k >> 8) & 3, wd = k >> 10;
      int n = nt * 16 + (l & 15), m0 = mt * 16 + 4 * (l >> 4);
      maskT[k] = *(const float4*)(mask_g + (size_t)wd * 4096 + n * 64 + m0);
    }
  }
}

#define XROW 528

// ===================== K1: QKV + attention -> O fragments =====================
// 256 threads = 4 waves; wave wv owns channels [wv*64, wv*64+64) = heads 2wv, 2wv+1.
// Of: uint4[((b*8+h)*4+nt)*64 + l] : lane(lr,lq) = O[t=16nt+lr][cin=h*32+8lq..+7]
#define K1_LDS 67584  // XREF [64][264]bf16 + XADJ [64][264]bf16

__global__ __launch_bounds__(256, 2) void qkvattn_kern(
    const float* __restrict__ xr_g, const float* __restrict__ xa_g,
    const float* __restrict__ qb_g, const float* __restrict__ kvb_g,
    const uint4* __restrict__ qwt, const uint4* __restrict__ kwt,
    const uint4* __restrict__ vwt,
    const float4* __restrict__ biasT, const float4* __restrict__ maskT,
    uint4* __restrict__ Of, int nW) {
  extern __shared__ char smem[];
  const int tid = threadIdx.x;
  const int l = tid & 63, wv = tid >> 6;  // wv 0..3
  const int lr = l & 15, lq = l >> 4;
  const int b = blockIdx.x;
  const int wd = b % nW;
  const float scale = 0.17677669529663687f;  // 1/sqrt(32)
  const int srcA = lr + 32 * (lq & 1);
  const int srcB = srcA + 16;
  const bool hi = (lq >> 1) != 0;

  // ---- stage ref -> XREF(0), adj -> XADJ(33792) as bf16 [64][264]
  {
    const float* refb = xr_g + (size_t)b * 16384;
    const float* adjb = xa_g + (size_t)b * 16384;
#pragma unroll 4
    for (int it = 0; it < 16; ++it) {
      int flat = it * 256 + tid;
      int t = flat >> 6, c4 = (flat & 63) << 2;
      float4 vr = *(const float4*)(refb + t * 256 + c4);
      float4 va = *(const float4*)(adjb + t * 256 + c4);
      uint2 wr_, wa_;
      wr_.x = pack2(vr.x, vr.y);
      wr_.y = pack2(vr.z, vr.w);
      wa_.x = pack2(va.x, va.y);
      wa_.y = pack2(va.z, va.w);
      *(uint2*)(smem + t * XROW + c4 * 2) = wr_;
      *(uint2*)(smem + 33792 + t * XROW + c4 * 2) = wa_;
    }
  }
  __syncthreads();  // the ONLY barrier

  bf16x8 bfr[2][4], afr[2][4];

  // ---- Q-gemm: 64 channels (4 row-tiles) -> xpose -> bfr[h2][nt]
  {
    f32x4 qacc[4][4];
#pragma unroll
    for (int i = 0; i < 4; ++i)
#pragma unroll
      for (int j = 0; j < 4; ++j) qacc[i][j] = {0.f, 0.f, 0.f, 0.f};
#pragma unroll 2
    for (int kk = 0; kk < 8; ++kk) {
      bf16x8 a0 = *(const bf16x8*)&qwt[((wv * 4 + 0) * 8 + kk) * 64 + l];
      bf16x8 a1 = *(const bf16x8*)&qwt[((wv * 4 + 1) * 8 + kk) * 64 + l];
      bf16x8 a2 = *(const bf16x8*)&qwt[((wv * 4 + 2) * 8 + kk) * 64 + l];
      bf16x8 a3 = *(const bf16x8*)&qwt[((wv * 4 + 3) * 8 + kk) * 64 + l];
      int c = kk * 32 + 8 * lq;
#pragma unroll
      for (int nt = 0; nt < 4; ++nt) {
        bf16x8 bt = *(const bf16x8*)(smem + (nt * 16 + lr) * XROW + c * 2);
        qacc[0][nt] = __builtin_amdgcn_mfma_f32_16x16x32_bf16(a0, bt, qacc[0][nt], 0, 0, 0);
        qacc[1][nt] = __builtin_amdgcn_mfma_f32_16x16x32_bf16(a1, bt, qacc[1][nt], 0, 0, 0);
        qacc[2][nt] = __builtin_amdgcn_mfma_f32_16x16x32_bf16(a2, bt, qacc[2][nt], 0, 0, 0);
        qacc[3][nt] = __builtin_amdgcn_mfma_f32_16x16x32_bf16(a3, bt, qacc[3][nt], 0, 0, 0);
      }
    }
#pragma unroll
    for (int rt = 0; rt < 4; ++rt) {
      float4 b4 = *(const float4*)(qb_g + wv * 64 + rt * 16 + 4 * lq);
#pragma unroll
      for (int nt = 0; nt < 4; ++nt) {
        qacc[rt][nt][0] = (qacc[rt][nt][0] + b4.x) * scale;
        qacc[rt][nt][1] = (qacc[rt][nt][1] + b4.y) * scale;
        qacc[rt][nt][2] = (qacc[rt][nt][2] + b4.z) * scale;
        qacc[rt][nt][3] = (qacc[rt][nt][3] + b4.w) * scale;
      }
    }
#pragma unroll
    for (int h2 = 0; h2 < 2; ++h2)
#pragma unroll
      for (int nt = 0; nt < 4; ++nt)
        bfr[h2][nt] = xpose_tile(qacc[2 * h2][nt], qacc[2 * h2 + 1][nt], srcA, srcB, hi);
  }

  // ---- K-gemm -> xpose -> afr[h2][mt]
  {
    f32x4 kacc[4][4];
#pragma unroll
    for (int i = 0; i < 4; ++i)
#pragma unroll
      for (int j = 0; j < 4; ++j) kacc[i][j] = {0.f, 0.f, 0.f, 0.f};
#pragma unroll 2
    for (int kk = 0; kk < 8; ++kk) {
      bf16x8 a0 = *(const bf16x8*)&kwt[((wv * 4 + 0) * 8 + kk) * 64 + l];
      bf16x8 a1 = *(const bf16x8*)&kwt[((wv * 4 + 1) * 8 + kk) * 64 + l];
      bf16x8 a2 = *(const bf16x8*)&kwt[((wv * 4 + 2) * 8 + kk) * 64 + l];
      bf16x8 a3 = *(const bf16x8*)&kwt[((wv * 4 + 3) * 8 + kk) * 64 + l];
      int c = kk * 32 + 8 * lq;
#pragma unroll
      for (int nt = 0; nt < 4; ++nt) {
        bf16x8 bt = *(const bf16x8*)(smem + 33792 + (nt * 16 + lr) * XROW + c * 2);
        kacc[0][nt] = __builtin_amdgcn_mfma_f32_16x16x32_bf16(a0, bt, kacc[0][nt], 0, 0, 0);
        kacc[1][nt] = __builtin_amdgcn_mfma_f32_16x16x32_bf16(a1, bt, kacc[1][nt], 0, 0, 0);
        kacc[2][nt] = __builtin_amdgcn_mfma_f32_16x16x32_bf16(a2, bt, kacc[2][nt], 0, 0, 0);
        kacc[3][nt] = __builtin_amdgcn_mfma_f32_16x16x32_bf16(a3, bt, kacc[3][nt], 0, 0, 0);
      }
    }
#pragma unroll
    for (int rt = 0; rt < 4; ++rt) {
      float4 b4 = *(const float4*)(kvb_g + wv * 64 + rt * 16 + 4 * lq);
#pragma unroll
      for (int nt = 0; nt < 4; ++nt) {
        kacc[rt][nt][0] += b4.x;
        kacc[rt][nt][1] += b4.y;
        kacc[rt][nt][2] += b4.z;
        kacc[rt][nt][3] += b4.w;
      }
    }
#pragma unroll
    for (int h2 = 0; h2 < 2; ++h2)
#pragma unroll
      for (int nt = 0; nt < 4; ++nt)
        afr[h2][nt] = xpose_tile(kacc[2 * h2][nt], kacc[2 * h2 + 1][nt], srcA, srcB, hi);
  }

  // ---- V-gemm (non-transposed) -> xpose -> vfr[h2][kk][cg]
  bf16x8 vfr[2][2][2];
  {
    f32x4 vacc[4][4];  // [mt tok-tile][ct chan-16-block]
#pragma unroll
    for (int i = 0; i < 4; ++i)
#pragma unroll
      for (int j = 0; j < 4; ++j) vacc[i][j] = {0.f, 0.f, 0.f, 0.f};
#pragma unroll 2
    for (int kk = 0; kk < 8; ++kk) {
      bf16x8 b0 = *(const bf16x8*)&vwt[((wv * 4 + 0) * 8 + kk) * 64 + l];
      bf16x8 b1 = *(const bf16x8*)&vwt[((wv * 4 + 1) * 8 + kk) * 64 + l];
      bf16x8 b2 = *(const bf16x8*)&vwt[((wv * 4 + 2) * 8 + kk) * 64 + l];
      bf16x8 b3 = *(const bf16x8*)&vwt[((wv * 4 + 3) * 8 + kk) * 64 + l];
      int c = kk * 32 + 8 * lq;
#pragma unroll
      for (int mt = 0; mt < 4; ++mt) {
        bf16x8 at = *(const bf16x8*)(smem + 33792 + (mt * 16 + lr) * XROW + c * 2);
        vacc[mt][0] = __builtin_amdgcn_mfma_f32_16x16x32_bf16(at, b0, vacc[mt][0], 0, 0, 0);
        vacc[mt][1] = __builtin_amdgcn_mfma_f32_16x16x32_bf16(at, b1, vacc[mt][1], 0, 0, 0);
        vacc[mt][2] = __builtin_amdgcn_mfma_f32_16x16x32_bf16(at, b2, vacc[mt][2], 0, 0, 0);
        vacc[mt][3] = __builtin_amdgcn_mfma_f32_16x16x32_bf16(at, b3, vacc[mt][3], 0, 0, 0);
      }
    }
#pragma unroll
    for (int ct = 0; ct < 4; ++ct) {
      float bv = kvb_g[256 + wv * 64 + ct * 16 + lr];
#pragma unroll
      for (int mt = 0; mt < 4; ++mt)
#pragma unroll
        for (int j = 0; j < 4; ++j) vacc[mt][ct][j] += bv;
    }
#pragma unroll
    for (int h2 = 0; h2 < 2; ++h2)
#pragma unroll
      for (int kk = 0; kk < 2; ++kk)
#pragma unroll
        for (int cg = 0; cg < 2; ++cg)
          vfr[h2][kk][cg] =
              xpose_tile(vacc[2 * kk][2 * h2 + cg], vacc[2 * kk + 1][2 * h2 + cg], srcA, srcB, hi);
  }

  // ---- per-head attention (sequential; sacc reused; compile-time indices)
#pragma unroll
  for (int h2 = 0; h2 < 2; ++h2) {
    const int h = wv * 2 + h2;

    // QK^T with C = bias + mask (coalesced fragment-layout loads)
    f32x4 sacc[4][4];  // attnT[m=16mt+4lq+j][n=16nt+lr]
    {
      const float4* bT = biasT + (size_t)h * 1024;
      const float4* mT = maskT + (size_t)wd * 1024;
#pragma unroll
      for (int nt = 0; nt < 4; ++nt) {
#pragma unroll
        for (int mt = 0; mt < 4; ++mt) {
          float4 bi = bT[(nt * 4 + mt) * 64 + l];
          float4 m4 = mT[(nt * 4 + mt) * 64 + l];
          sacc[mt][nt][0] = bi.x + m4.x;
          sacc[mt][nt][1] = bi.y + m4.y;
          sacc[mt][nt][2] = bi.z + m4.z;
          sacc[mt][nt][3] = bi.w + m4.w;
        }
      }
    }
#pragma unroll
    for (int mt = 0; mt < 4; ++mt)
#pragma unroll
      for (int nt = 0; nt < 4; ++nt)
        sacc[mt][nt] = __builtin_amdgcn_mfma_f32_16x16x32_bf16(afr[h2][mt], bfr[h2][nt],
                                                               sacc[mt][nt], 0, 0, 0);

    // softmax (register-only)
    float rden[4];
#pragma unroll
    for (int nt = 0; nt < 4; ++nt) {
      float lmx = -1e30f;
#pragma unroll
      for (int mt = 0; mt < 4; ++mt)
        lmx = fmaxf(lmx, fmaxf(fmaxf(sacc[mt][nt][0], sacc[mt][nt][1]),
                               fmaxf(sacc[mt][nt][2], sacc[mt][nt][3])));
      lmx = fmaxf(lmx, __shfl_xor(lmx, 16));
      lmx = fmaxf(lmx, __shfl_xor(lmx, 32));
      float ls = 0.f;
#pragma unroll
      for (int mt = 0; mt < 4; ++mt) {
#pragma unroll
        for (int j = 0; j < 4; ++j) {
          float e = __expf(sacc[mt][nt][j] - lmx);
          sacc[mt][nt][j] = e;
          ls += e;
        }
      }
      ls += __shfl_xor(ls, 16);
      ls += __shfl_xor(ls, 32);
      rden[nt] = 1.0f / ls;
    }

    // P transpose -> pfr[kk][nt]
    bf16x8 pfr[2][4];
#pragma unroll
    for (int kk = 0; kk < 2; ++kk)
#pragma unroll
      for (int nt = 0; nt < 4; ++nt)
        pfr[kk][nt] = xpose_tile(sacc[2 * kk][nt], sacc[2 * kk + 1][nt], srcA, srcB, hi);

    // PV
    f32x4 oacc[2][4];
#pragma unroll
    for (int i = 0; i < 2; ++i)
#pragma unroll
      for (int j = 0; j < 4; ++j) oacc[i][j] = {0.f, 0.f, 0.f, 0.f};
#pragma unroll
    for (int kk = 0; kk < 2; ++kk)
#pragma unroll
      for (int nt = 0; nt < 4; ++nt) {
        oacc[0][nt] = __builtin_amdgcn_mfma_f32_16x16x32_bf16(vfr[h2][kk][0], pfr[kk][nt],
                                                              oacc[0][nt], 0, 0, 0);
        oacc[1][nt] = __builtin_amdgcn_mfma_f32_16x16x32_bf16(vfr[h2][kk][1], pfr[kk][nt],
                                                              oacc[1][nt], 0, 0, 0);
      }

    // normalize -> xpose -> Of fragments
#pragma unroll
    for (int nt = 0; nt < 4; ++nt) {
      float r = rden[nt];
#pragma unroll
      for (int j = 0; j < 4; ++j) {
        oacc[0][nt][j] *= r;
        oacc[1][nt][j] *= r;
      }
      bf16x8 f = xpose_tile(oacc[0][nt], oacc[1][nt], srcA, srcB, hi);
      Of[((size_t)(b * 8 + h) * 4 + nt) * 64 + l] = __builtin_bit_cast(uint4, f);
    }
  }
}

// ===================== K2: output projection (no LDS, no barrier) =====================
__global__ __launch_bounds__(512, 4) void proj_kern(
    const uint4* __restrict__ Of, const uint4* __restrict__ pjwt,
    const float* __restrict__ pb_g, float* __restrict__ out_g) {
  const int tid = threadIdx.x;
  const int l = tid & 63, wv = tid >> 6;
  const int lr = l & 15, lq = l >> 4;
  const int b = blockIdx.x;

  f32x4 acc[4][2];
#pragma unroll
  for (int i = 0; i < 4; ++i)
#pragma unroll
    for (int j = 0; j < 2; ++j) acc[i][j] = {0.f, 0.f, 0.f, 0.f};
#pragma unroll 2
  for (int kk = 0; kk < 8; ++kk) {
    bf16x8 b0 = *(const bf16x8*)&pjwt[((wv * 2 + 0) * 8 + kk) * 64 + l];
    bf16x8 b1 = *(const bf16x8*)&pjwt[((wv * 2 + 1) * 8 + kk) * 64 + l];
#pragma unroll
    for (int mt = 0; mt < 4; ++mt) {
      bf16x8 at = __builtin_bit_cast(bf16x8, Of[((size_t)(b * 8 + kk) * 4 + mt) * 64 + l]);
      acc[mt][0] = __builtin_amdgcn_mfma_f32_16x16x32_bf16(at, b0, acc[mt][0], 0, 0, 0);
      acc[mt][1] = __builtin_amdgcn_mfma_f32_16x16x32_bf16(at, b1, acc[mt][1], 0, 0, 0);
    }
  }
  float* outb = out_g + (size_t)b * 16384;
#pragma unroll
  for (int ntl = 0; ntl < 2; ++ntl) {
    int c = wv * 32 + ntl * 16 + lr;
    float pbv = pb_g[c];
#pragma unroll
    for (int mt = 0; mt < 4; ++mt) {
      int t = mt * 16 + 4 * lq;
      outb[(t + 0) * 256 + c] = acc[mt][ntl][0] + pbv;
      outb[(t + 1) * 256 + c] = acc[mt][ntl][1] + pbv;
      outb[(t + 2) * 256 + c] = acc[mt][ntl][2] + pbv;
      outb[(t + 3) * 256 + c] = acc[mt][ntl][3] + pbv;
    }
  }
}

extern "C" void kernel_launch(void* const* d_in, const int* in_sizes, int n_in,
                              void* d_out, int out_size, void* d_ws, size_t ws_size,
                              hipStream_t stream) {
  const float* ref = (const float*)d_in[0];
  const float* adj = (const float*)d_in[1];
  const float* mask = (const float*)d_in[2];
  const float* q_w = (const float*)d_in[3];
  const float* q_b = (const float*)d_in[4];
  const float* kv_w = (const float*)d_in[5];
  const float* kv_b = (const float*)d_in[6];
  const float* proj_w = (const float*)d_in[7];
  const float* proj_b = (const float*)d_in[8];
  const float* rpb = (const float*)d_in[9];

  int B = in_sizes[0] / 16384;  // 4096 windows
  int nW = in_sizes[2] / 4096;  // 1024

  // workspace layout
  uint4* qwt = (uint4*)d_ws;          // 512 KB
  uint4* kwt = qwt + 32768;           // 512 KB
  uint4* vwt = kwt + 32768;           // 512 KB
  uint4* pjwt = vwt + 32768;          // 512 KB
  float4* biasT = (float4*)(pjwt + 32768);  // 128 KB
  float4* maskT = biasT + 8192;             // nW*16 KB (16.7 MB)
  uint4* Of = (uint4*)((char*)d_ws + (32u << 20));  // 134 MB at 32 MB offset

  int prep_total = 139264 + nW * 1024;
  prep_kern<<<(prep_total + 255) / 256, 256, 0, stream>>>(q_w, kv_w, proj_w, rpb, mask, qwt,
                                                          kwt, vwt, pjwt, biasT, maskT, nW);

  hipFuncSetAttribute((const void*)qkvattn_kern, hipFuncAttributeMaxDynamicSharedMemorySize,
                      K1_LDS);
  qkvattn_kern<<<B, 256, K1_LDS, stream>>>(ref, adj, q_b, kv_b, qwt, kwt, vwt, biasT, maskT,
                                           Of, nW);
  proj_kern<<<B, 512, 0, stream>>>(Of, pjwt, proj_b, (float*)d_out);
}

// Round 12
// 316.739 us; speedup vs baseline: 2.4298x; 1.2821x over previous
//
#include <hip/hip_runtime.h>

typedef unsigned short u16;
typedef unsigned int u32;
typedef float f32x4 __attribute__((ext_vector_type(4)));
typedef __bf16 bf16x8 __attribute__((ext_vector_type(8)));

// one-instruction packed f32x2 -> bf16x2 (RNE)
__device__ __forceinline__ u32 pack2(float a, float b) {
  u32 r;
  asm("v_cvt_pk_bf16_f32 %0, %1, %2" : "=v"(r) : "v"(a), "v"(b));
  return r;
}

// in-wave transpose of a pair of gemmT acc tiles into an MFMA fragment bf16x8
__device__ __forceinline__ bf16x8 xpose_tile(const f32x4 t0, const f32x4 t1,
                                             int srcA, int srcB, bool hi) {
  u32 s0 = pack2(t0[0], t0[1]);
  u32 s1 = pack2(t0[2], t0[3]);
  u32 s2 = pack2(t1[0], t1[1]);
  u32 s3 = pack2(t1[2], t1[3]);
  u32 a00 = (u32)__shfl((int)s0, srcA), a20 = (u32)__shfl((int)s2, srcA);
  u32 a01 = (u32)__shfl((int)s1, srcA), a21 = (u32)__shfl((int)s3, srcA);
  u32 b00 = (u32)__shfl((int)s0, srcB), b20 = (u32)__shfl((int)s2, srcB);
  u32 b01 = (u32)__shfl((int)s1, srcB), b21 = (u32)__shfl((int)s3, srcB);
  uint4 u;
  u.x = hi ? a20 : a00;
  u.y = hi ? a21 : a01;
  u.z = hi ? b20 : b00;
  u.w = hi ? b21 : b01;
  return __builtin_bit_cast(bf16x8, u);
}

// ---- prep: permute weights/bias/mask into per-wave fragment order (coalesced loads)
// weight frag: dst[((R*8+kk)*64+l)] = W[ro + R*16 + (l&15)][kk*32 + 8*(l>>4) .. +7] (bf16x8)
// bias/mask frag: dst[((·*4+nt)*4+mt)*64+l] = M[nt*16+(l&15)][mt*16+4*(l>>4) .. +3] (float4)
__global__ void prep_kern(const float* __restrict__ qw_f, const float* __restrict__ kvw_f,
                          const float* __restrict__ pjw_f, const float* __restrict__ rpb,
                          const float* __restrict__ mask_g,
                          uint4* __restrict__ qwt, uint4* __restrict__ kwt,
                          uint4* __restrict__ vwt, uint4* __restrict__ pjwt,
                          float4* __restrict__ biasT, float4* __restrict__ maskT, int nW) {
  int i = blockIdx.x * 256 + threadIdx.x;
  auto wxf = [&](const float* W, int ro, int idx, uint4* dst) {
    int l = idx & 63, kk = (idx >> 6) & 7, R = idx >> 9;
    const float* s = W + (ro + R * 16 + (l & 15)) * 256 + kk * 32 + 8 * (l >> 4);
    uint4 o;
    o.x = pack2(s[0], s[1]);
    o.y = pack2(s[2], s[3]);
    o.z = pack2(s[4], s[5]);
    o.w = pack2(s[6], s[7]);
    dst[idx] = o;
  };
  if (i < 32768) {
    wxf(qw_f, 0, i, qwt);
  } else if (i < 65536) {
    wxf(kvw_f, 0, i - 32768, kwt);
  } else if (i < 98304) {
    wxf(kvw_f, 256, i - 65536, vwt);
  } else if (i < 131072) {
    wxf(pjw_f, 0, i - 98304, pjwt);
  } else if (i < 139264) {
    int j = i - 131072;  // [h][nt][mt][l]
    int l = j & 63, mt = (j >> 6) & 3, nt = (j >> 8) & 3, h = j >> 10;
    int n = nt * 16 + (l & 15), m0 = mt * 16 + 4 * (l >> 4);
    float4 o;
    float* po = (float*)&o;
#pragma unroll
    for (int e = 0; e < 4; ++e) {
      int m = m0 + e;
      int rp = ((n >> 3) - (m >> 3) + 7) * 15 + ((n & 7) - (m & 7) + 7);
      po[e] = rpb[rp * 8 + h];
    }
    biasT[j] = o;
  } else {
    int k = i - 139264;  // [wd][nt][mt][l]
    if (k < nW * 1024) {
      int l = k & 63, mt = (k >> 6) & 3, nt = (k >> 8) & 3, wd = k >> 10;
      int n = nt * 16 + (l & 15), m0 = mt * 16 + 4 * (l >> 4);
      maskT[k] = *(const float4*)(mask_g + (size_t)wd * 4096 + n * 64 + m0);
    }
  }
}

#define XROW 528

// ===================== K1: QKV + attention + proj (fully fused) =====================
// 256 threads = 4 waves; wave wv owns channels [wv*64, wv*64+64) = heads 2wv, 2wv+1.
// LDS: XREF [64][264]bf16 (reused as O tile after B2) + XADJ [64][264]bf16.
#define K1_LDS 67584

__global__ __launch_bounds__(256, 2) void winattn_kern(
    const float* __restrict__ xr_g, const float* __restrict__ xa_g,
    const float* __restrict__ qb_g, const float* __restrict__ kvb_g,
    const float* __restrict__ pb_g,
    const uint4* __restrict__ qwt, const uint4* __restrict__ kwt,
    const uint4* __restrict__ vwt, const uint4* __restrict__ pjwt,
    const float4* __restrict__ biasT, const float4* __restrict__ maskT,
    float* __restrict__ out_g, int nW) {
  extern __shared__ char smem[];
  const int tid = threadIdx.x;
  const int l = tid & 63, wv = tid >> 6;  // wv 0..3
  const int lr = l & 15, lq = l >> 4;
  const int b = blockIdx.x;
  const int wd = b % nW;
  const float scale = 0.17677669529663687f;  // 1/sqrt(32)
  const int srcA = lr + 32 * (lq & 1);
  const int srcB = srcA + 16;
  const bool hi = (lq >> 1) != 0;

  // ---- stage ref -> XREF(0), adj -> XADJ(33792) as bf16 [64][264]
  {
    const float* refb = xr_g + (size_t)b * 16384;
    const float* adjb = xa_g + (size_t)b * 16384;
#pragma unroll 4
    for (int it = 0; it < 16; ++it) {
      int flat = it * 256 + tid;
      int t = flat >> 6, c4 = (flat & 63) << 2;
      float4 vr = *(const float4*)(refb + t * 256 + c4);
      float4 va = *(const float4*)(adjb + t * 256 + c4);
      uint2 wr_, wa_;
      wr_.x = pack2(vr.x, vr.y);
      wr_.y = pack2(vr.z, vr.w);
      wa_.x = pack2(va.x, va.y);
      wa_.y = pack2(va.z, va.w);
      *(uint2*)(smem + t * XROW + c4 * 2) = wr_;
      *(uint2*)(smem + 33792 + t * XROW + c4 * 2) = wa_;
    }
  }
  __syncthreads();  // B1: stage complete

  bf16x8 bfr[2][4], afr[2][4];

  // ---- Q-gemm: 64 channels (4 row-tiles) -> xpose -> bfr[h2][nt]
  {
    f32x4 qacc[4][4];
#pragma unroll
    for (int i = 0; i < 4; ++i)
#pragma unroll
      for (int j = 0; j < 4; ++j) qacc[i][j] = {0.f, 0.f, 0.f, 0.f};
#pragma unroll 2
    for (int kk = 0; kk < 8; ++kk) {
      bf16x8 a0 = *(const bf16x8*)&qwt[((wv * 4 + 0) * 8 + kk) * 64 + l];
      bf16x8 a1 = *(const bf16x8*)&qwt[((wv * 4 + 1) * 8 + kk) * 64 + l];
      bf16x8 a2 = *(const bf16x8*)&qwt[((wv * 4 + 2) * 8 + kk) * 64 + l];
      bf16x8 a3 = *(const bf16x8*)&qwt[((wv * 4 + 3) * 8 + kk) * 64 + l];
      int c = kk * 32 + 8 * lq;
#pragma unroll
      for (int nt = 0; nt < 4; ++nt) {
        bf16x8 bt = *(const bf16x8*)(smem + (nt * 16 + lr) * XROW + c * 2);
        qacc[0][nt] = __builtin_amdgcn_mfma_f32_16x16x32_bf16(a0, bt, qacc[0][nt], 0, 0, 0);
        qacc[1][nt] = __builtin_amdgcn_mfma_f32_16x16x32_bf16(a1, bt, qacc[1][nt], 0, 0, 0);
        qacc[2][nt] = __builtin_amdgcn_mfma_f32_16x16x32_bf16(a2, bt, qacc[2][nt], 0, 0, 0);
        qacc[3][nt] = __builtin_amdgcn_mfma_f32_16x16x32_bf16(a3, bt, qacc[3][nt], 0, 0, 0);
      }
    }
#pragma unroll
    for (int rt = 0; rt < 4; ++rt) {
      float4 b4 = *(const float4*)(qb_g + wv * 64 + rt * 16 + 4 * lq);
#pragma unroll
      for (int nt = 0; nt < 4; ++nt) {
        qacc[rt][nt][0] = (qacc[rt][nt][0] + b4.x) * scale;
        qacc[rt][nt][1] = (qacc[rt][nt][1] + b4.y) * scale;
        qacc[rt][nt][2] = (qacc[rt][nt][2] + b4.z) * scale;
        qacc[rt][nt][3] = (qacc[rt][nt][3] + b4.w) * scale;
      }
    }
#pragma unroll
    for (int h2 = 0; h2 < 2; ++h2)
#pragma unroll
      for (int nt = 0; nt < 4; ++nt)
        bfr[h2][nt] = xpose_tile(qacc[2 * h2][nt], qacc[2 * h2 + 1][nt], srcA, srcB, hi);
  }
  __syncthreads();  // B2: XREF reads done; region becomes O tile

  // ---- K-gemm -> xpose -> afr[h2][mt]
  {
    f32x4 kacc[4][4];
#pragma unroll
    for (int i = 0; i < 4; ++i)
#pragma unroll
      for (int j = 0; j < 4; ++j) kacc[i][j] = {0.f, 0.f, 0.f, 0.f};
#pragma unroll 2
    for (int kk = 0; kk < 8; ++kk) {
      bf16x8 a0 = *(const bf16x8*)&kwt[((wv * 4 + 0) * 8 + kk) * 64 + l];
      bf16x8 a1 = *(const bf16x8*)&kwt[((wv * 4 + 1) * 8 + kk) * 64 + l];
      bf16x8 a2 = *(const bf16x8*)&kwt[((wv * 4 + 2) * 8 + kk) * 64 + l];
      bf16x8 a3 = *(const bf16x8*)&kwt[((wv * 4 + 3) * 8 + kk) * 64 + l];
      int c = kk * 32 + 8 * lq;
#pragma unroll
      for (int nt = 0; nt < 4; ++nt) {
        bf16x8 bt = *(const bf16x8*)(smem + 33792 + (nt * 16 + lr) * XROW + c * 2);
        kacc[0][nt] = __builtin_amdgcn_mfma_f32_16x16x32_bf16(a0, bt, kacc[0][nt], 0, 0, 0);
        kacc[1][nt] = __builtin_amdgcn_mfma_f32_16x16x32_bf16(a1, bt, kacc[1][nt], 0, 0, 0);
        kacc[2][nt] = __builtin_amdgcn_mfma_f32_16x16x32_bf16(a2, bt, kacc[2][nt], 0, 0, 0);
        kacc[3][nt] = __builtin_amdgcn_mfma_f32_16x16x32_bf16(a3, bt, kacc[3][nt], 0, 0, 0);
      }
    }
#pragma unroll
    for (int rt = 0; rt < 4; ++rt) {
      float4 b4 = *(const float4*)(kvb_g + wv * 64 + rt * 16 + 4 * lq);
#pragma unroll
      for (int nt = 0; nt < 4; ++nt) {
        kacc[rt][nt][0] += b4.x;
        kacc[rt][nt][1] += b4.y;
        kacc[rt][nt][2] += b4.z;
        kacc[rt][nt][3] += b4.w;
      }
    }
#pragma unroll
    for (int h2 = 0; h2 < 2; ++h2)
#pragma unroll
      for (int nt = 0; nt < 4; ++nt)
        afr[h2][nt] = xpose_tile(kacc[2 * h2][nt], kacc[2 * h2 + 1][nt], srcA, srcB, hi);
  }

  // ---- V-gemm (non-transposed) -> xpose -> vfr[h2][kk][cg]
  bf16x8 vfr[2][2][2];
  {
    f32x4 vacc[4][4];  // [mt tok-tile][ct chan-16-block]
#pragma unroll
    for (int i = 0; i < 4; ++i)
#pragma unroll
      for (int j = 0; j < 4; ++j) vacc[i][j] = {0.f, 0.f, 0.f, 0.f};
#pragma unroll 2
    for (int kk = 0; kk < 8; ++kk) {
      bf16x8 b0 = *(const bf16x8*)&vwt[((wv * 4 + 0) * 8 + kk) * 64 + l];
      bf16x8 b1 = *(const bf16x8*)&vwt[((wv * 4 + 1) * 8 + kk) * 64 + l];
      bf16x8 b2 = *(const bf16x8*)&vwt[((wv * 4 + 2) * 8 + kk) * 64 + l];
      bf16x8 b3 = *(const bf16x8*)&vwt[((wv * 4 + 3) * 8 + kk) * 64 + l];
      int c = kk * 32 + 8 * lq;
#pragma unroll
      for (int mt = 0; mt < 4; ++mt) {
        bf16x8 at = *(const bf16x8*)(smem + 33792 + (mt * 16 + lr) * XROW + c * 2);
        vacc[mt][0] = __builtin_amdgcn_mfma_f32_16x16x32_bf16(at, b0, vacc[mt][0], 0, 0, 0);
        vacc[mt][1] = __builtin_amdgcn_mfma_f32_16x16x32_bf16(at, b1, vacc[mt][1], 0, 0, 0);
        vacc[mt][2] = __builtin_amdgcn_mfma_f32_16x16x32_bf16(at, b2, vacc[mt][2], 0, 0, 0);
        vacc[mt][3] = __builtin_amdgcn_mfma_f32_16x16x32_bf16(at, b3, vacc[mt][3], 0, 0, 0);
      }
    }
#pragma unroll
    for (int ct = 0; ct < 4; ++ct) {
      float bv = kvb_g[256 + wv * 64 + ct * 16 + lr];
#pragma unroll
      for (int mt = 0; mt < 4; ++mt)
#pragma unroll
        for (int j = 0; j < 4; ++j) vacc[mt][ct][j] += bv;
    }
#pragma unroll
    for (int h2 = 0; h2 < 2; ++h2)
#pragma unroll
      for (int kk = 0; kk < 2; ++kk)
#pragma unroll
        for (int cg = 0; cg < 2; ++cg)
          vfr[h2][kk][cg] =
              xpose_tile(vacc[2 * kk][2 * h2 + cg], vacc[2 * kk + 1][2 * h2 + cg], srcA, srcB, hi);
  }

  // ---- per-head attention; O written to LDS O-tile (XREF region)
#pragma unroll
  for (int h2 = 0; h2 < 2; ++h2) {
    const int h = wv * 2 + h2;

    // QK^T with C = bias + mask (coalesced fragment-layout loads)
    f32x4 sacc[4][4];  // attnT[m=16mt+4lq+j][n=16nt+lr]
    {
      const float4* bT = biasT + (size_t)h * 1024;
      const float4* mT = maskT + (size_t)wd * 1024;
#pragma unroll
      for (int nt = 0; nt < 4; ++nt) {
#pragma unroll
        for (int mt = 0; mt < 4; ++mt) {
          float4 bi = bT[(nt * 4 + mt) * 64 + l];
          float4 m4 = mT[(nt * 4 + mt) * 64 + l];
          sacc[mt][nt][0] = bi.x + m4.x;
          sacc[mt][nt][1] = bi.y + m4.y;
          sacc[mt][nt][2] = bi.z + m4.z;
          sacc[mt][nt][3] = bi.w + m4.w;
        }
      }
    }
#pragma unroll
    for (int mt = 0; mt < 4; ++mt)
#pragma unroll
      for (int nt = 0; nt < 4; ++nt)
        sacc[mt][nt] = __builtin_amdgcn_mfma_f32_16x16x32_bf16(afr[h2][mt], bfr[h2][nt],
                                                               sacc[mt][nt], 0, 0, 0);

    // softmax (register-only)
    float rden[4];
#pragma unroll
    for (int nt = 0; nt < 4; ++nt) {
      float lmx = -1e30f;
#pragma unroll
      for (int mt = 0; mt < 4; ++mt)
        lmx = fmaxf(lmx, fmaxf(fmaxf(sacc[mt][nt][0], sacc[mt][nt][1]),
                               fmaxf(sacc[mt][nt][2], sacc[mt][nt][3])));
      lmx = fmaxf(lmx, __shfl_xor(lmx, 16));
      lmx = fmaxf(lmx, __shfl_xor(lmx, 32));
      float ls = 0.f;
#pragma unroll
      for (int mt = 0; mt < 4; ++mt) {
#pragma unroll
        for (int j = 0; j < 4; ++j) {
          float e = __expf(sacc[mt][nt][j] - lmx);
          sacc[mt][nt][j] = e;
          ls += e;
        }
      }
      ls += __shfl_xor(ls, 16);
      ls += __shfl_xor(ls, 32);
      rden[nt] = 1.0f / ls;
    }

    // P transpose -> pfr[kk][nt]
    bf16x8 pfr[2][4];
#pragma unroll
    for (int kk = 0; kk < 2; ++kk)
#pragma unroll
      for (int nt = 0; nt < 4; ++nt)
        pfr[kk][nt] = xpose_tile(sacc[2 * kk][nt], sacc[2 * kk + 1][nt], srcA, srcB, hi);

    // PV -> oacc[cg][nt]: ch = h*32+16cg+4lq+j, tok = 16nt+lr
    f32x4 oacc[2][4];
#pragma unroll
    for (int i = 0; i < 2; ++i)
#pragma unroll
      for (int j = 0; j < 4; ++j) oacc[i][j] = {0.f, 0.f, 0.f, 0.f};
#pragma unroll
    for (int kk = 0; kk < 2; ++kk)
#pragma unroll
      for (int nt = 0; nt < 4; ++nt) {
        oacc[0][nt] = __builtin_amdgcn_mfma_f32_16x16x32_bf16(vfr[h2][kk][0], pfr[kk][nt],
                                                              oacc[0][nt], 0, 0, 0);
        oacc[1][nt] = __builtin_amdgcn_mfma_f32_16x16x32_bf16(vfr[h2][kk][1], pfr[kk][nt],
                                                              oacc[1][nt], 0, 0, 0);
      }

    // normalize + write O tile [t][c] into XREF region (no xpose needed)
#pragma unroll
    for (int cg = 0; cg < 2; ++cg) {
      int cb = h * 32 + cg * 16 + 4 * lq;
#pragma unroll
      for (int nt = 0; nt < 4; ++nt) {
        int n = nt * 16 + lr;
        float r = rden[nt];
        uint2 w;
        w.x = pack2(oacc[cg][nt][0] * r, oacc[cg][nt][1] * r);
        w.y = pack2(oacc[cg][nt][2] * r, oacc[cg][nt][3] * r);
        *(uint2*)(smem + n * XROW + cb * 2) = w;
      }
    }
  }
  __syncthreads();  // B3: O tile complete

  // ---- output projection from LDS O tile (wave owns out-channels wv*64..+64)
  {
    f32x4 acc[4][4];  // [mt tok-tile][rt out-chan-16-tile]
#pragma unroll
    for (int i = 0; i < 4; ++i)
#pragma unroll
      for (int j = 0; j < 4; ++j) acc[i][j] = {0.f, 0.f, 0.f, 0.f};
#pragma unroll 2
    for (int kk = 0; kk < 8; ++kk) {
      bf16x8 w0 = *(const bf16x8*)&pjwt[((wv * 4 + 0) * 8 + kk) * 64 + l];
      bf16x8 w1 = *(const bf16x8*)&pjwt[((wv * 4 + 1) * 8 + kk) * 64 + l];
      bf16x8 w2 = *(const bf16x8*)&pjwt[((wv * 4 + 2) * 8 + kk) * 64 + l];
      bf16x8 w3 = *(const bf16x8*)&pjwt[((wv * 4 + 3) * 8 + kk) * 64 + l];
      int c = kk * 32 + 8 * lq;
#pragma unroll
      for (int mt = 0; mt < 4; ++mt) {
        bf16x8 at = *(const bf16x8*)(smem + (mt * 16 + lr) * XROW + c * 2);
        acc[mt][0] = __builtin_amdgcn_mfma_f32_16x16x32_bf16(at, w0, acc[mt][0], 0, 0, 0);
        acc[mt][1] = __builtin_amdgcn_mfma_f32_16x16x32_bf16(at, w1, acc[mt][1], 0, 0, 0);
        acc[mt][2] = __builtin_amdgcn_mfma_f32_16x16x32_bf16(at, w2, acc[mt][2], 0, 0, 0);
        acc[mt][3] = __builtin_amdgcn_mfma_f32_16x16x32_bf16(at, w3, acc[mt][3], 0, 0, 0);
      }
    }
    float* outb = out_g + (size_t)b * 16384;
#pragma unroll
    for (int rt = 0; rt < 4; ++rt) {
      int c = wv * 64 + rt * 16 + lr;
      float pbv = pb_g[c];
#pragma unroll
      for (int mt = 0; mt < 4; ++mt) {
        int t = mt * 16 + 4 * lq;
        outb[(t + 0) * 256 + c] = acc[mt][rt][0] + pbv;
        outb[(t + 1) * 256 + c] = acc[mt][rt][1] + pbv;
        outb[(t + 2) * 256 + c] = acc[mt][rt][2] + pbv;
        outb[(t + 3) * 256 + c] = acc[mt][rt][3] + pbv;
      }
    }
  }
}

extern "C" void kernel_launch(void* const* d_in, const int* in_sizes, int n_in,
                              void* d_out, int out_size, void* d_ws, size_t ws_size,
                              hipStream_t stream) {
  const float* ref = (const float*)d_in[0];
  const float* adj = (const float*)d_in[1];
  const float* mask = (const float*)d_in[2];
  const float* q_w = (const float*)d_in[3];
  const float* q_b = (const float*)d_in[4];
  const float* kv_w = (const float*)d_in[5];
  const float* kv_b = (const float*)d_in[6];
  const float* proj_w = (const float*)d_in[7];
  const float* proj_b = (const float*)d_in[8];
  const float* rpb = (const float*)d_in[9];

  int B = in_sizes[0] / 16384;  // 4096 windows
  int nW = in_sizes[2] / 4096;  // 1024

  // workspace layout
  uint4* qwt = (uint4*)d_ws;                // 512 KB
  uint4* kwt = qwt + 32768;                 // 512 KB
  uint4* vwt = kwt + 32768;                 // 512 KB
  uint4* pjwt = vwt + 32768;                // 512 KB
  float4* biasT = (float4*)(pjwt + 32768);  // 128 KB
  float4* maskT = biasT + 8192;             // nW*16 KB (16.7 MB)

  int prep_total = 139264 + nW * 1024;
  prep_kern<<<(prep_total + 255) / 256, 256, 0, stream>>>(q_w, kv_w, proj_w, rpb, mask, qwt,
                                                          kwt, vwt, pjwt, biasT, maskT, nW);

  hipFuncSetAttribute((const void*)winattn_kern, hipFuncAttributeMaxDynamicSharedMemorySize,
                      K1_LDS);
  winattn_kern<<<B, 256, K1_LDS, stream>>>(ref, adj, q_b, kv_b, proj_b, qwt, kwt, vwt, pjwt,
                                           biasT, maskT, (float*)d_out, nW);
}